// Round 2
// baseline (16367.114 us; speedup 1.0000x reference)
//
#include <hip/hip_runtime.h>
#include <stdint.h>

#define U_NUM   100000
#define NNODES  200000
#define DIM     64
#define OUTDIM  256
#define NNZ     6400000

// Write ego (user||item, f32) into cols 0..63 of the 256-wide f32 output and
// zero cols 64..255. One float4 per thread.
__global__ void init_out(const float* __restrict__ user_emb,
                         const float* __restrict__ item_emb,
                         float* __restrict__ out) {
    int t = blockIdx.x * blockDim.x + threadIdx.x;   // NNODES*64 threads
    if (t >= NNODES * 64) return;
    int n = t >> 6;
    int c = (t & 63) << 2;                            // 0,4,...,252
    float4 v = make_float4(0.f, 0.f, 0.f, 0.f);
    if (c < DIM) {
        const float* s = (n < U_NUM) ? (user_emb + (size_t)n * DIM + c)
                                     : (item_emb + (size_t)(n - U_NUM) * DIM + c);
        v = *(const float4*)s;
    }
    *(float4*)(out + (size_t)n * OUTDIM + c) = v;
}

// One thread per (edge, 4 cols): float4 gather from prev-layer slice,
// scale by edge weight, 4x f32 atomic add into dst row of current slice.
// prev/cur are out + column offset of the respective 64-col slice.
__global__ void scatter_spmm(const int*   __restrict__ esrc,
                             const int*   __restrict__ edst,
                             const float* __restrict__ eval,
                             const float* __restrict__ prev,
                             float*       __restrict__ cur) {
    int t = blockIdx.x * blockDim.x + threadIdx.x;    // NNZ*16 = 102.4M threads
    if (t >= NNZ * 16) return;
    int e = t >> 4;
    int j = (t & 15) << 2;                            // 0,4,...,60
    int s = esrc[e];
    int d = edst[e];
    float v = eval[e];
    float4 x = *(const float4*)(prev + (size_t)s * OUTDIM + j);
    float* ap = cur + (size_t)d * OUTDIM + j;
    unsafeAtomicAdd(ap + 0, x.x * v);
    unsafeAtomicAdd(ap + 1, x.y * v);
    unsafeAtomicAdd(ap + 2, x.z * v);
    unsafeAtomicAdd(ap + 3, x.w * v);
}

extern "C" void kernel_launch(void* const* d_in, const int* in_sizes, int n_in,
                              void* d_out, int out_size, void* d_ws, size_t ws_size,
                              hipStream_t stream) {
    const float* user_emb = (const float*)d_in[0];
    const float* item_emb = (const float*)d_in[1];
    const float* eval     = (const float*)d_in[2];
    const int*   esrc     = (const int*)d_in[3];
    const int*   edst     = (const int*)d_in[4];
    float* out = (float*)d_out;                       // 200000 x 256 f32

    init_out<<<(NNODES * 64 + 255) / 256, 256, 0, stream>>>(user_emb, item_emb, out);

    for (int l = 1; l <= 3; ++l) {
        scatter_spmm<<<(NNZ * 16) / 256, 256, 0, stream>>>(
            esrc, edst, eval,
            out + (size_t)(l - 1) * DIM,
            out + (size_t)l * DIM);
    }
}

// Round 3
// 2147.141 us; speedup vs baseline: 7.6227x; 7.6227x over previous
//
#include <hip/hip_runtime.h>
#include <stdint.h>

#define U_NUM   100000
#define NNODES  200000
#define DIM     64
#define OUTDIM  256
#define NNZ     6400000

// ---------- ws layout ----------
// [0, 800000)                : uint32 rowcnt/rowptr/rowend (NNODES)
// [800000, 800000+NNZ*8)     : int2 pairs {src, f32bits(val)} sorted by dst
#define WS_NEEDED (800000 + (size_t)NNZ * 8)

// Copy ego (user||item) into cols 0..63. Layers 1..3 write cols 64..255 fully,
// so no zero-init of those is needed.
__global__ void init_out(const float* __restrict__ user_emb,
                         const float* __restrict__ item_emb,
                         float* __restrict__ out) {
    int t = blockIdx.x * blockDim.x + threadIdx.x;   // NNODES*16 threads
    if (t >= NNODES * 16) return;
    int n = t >> 4;
    int c = (t & 15) << 2;
    const float* s = (n < U_NUM) ? (user_emb + (size_t)n * DIM + c)
                                 : (item_emb + (size_t)(n - U_NUM) * DIM + c);
    *(float4*)(out + (size_t)n * OUTDIM + c) = *(const float4*)s;
}

__global__ void zero_cnt(uint32_t* __restrict__ cnt) {
    int t = blockIdx.x * blockDim.x + threadIdx.x;
    if (t < NNODES) cnt[t] = 0u;
}

__global__ void hist(const int* __restrict__ edst, uint32_t* __restrict__ cnt) {
    int e = blockIdx.x * blockDim.x + threadIdx.x;   // NNZ threads
    if (e < NNZ) atomicAdd(&cnt[edst[e]], 1u);
}

// Single-workgroup exclusive scan over NNODES counters, in place.
__global__ __launch_bounds__(1024) void scan_cnt(uint32_t* __restrict__ cnt) {
    __shared__ uint32_t lds[1024];
    __shared__ uint32_t s_carry;
    int t = threadIdx.x;
    if (t == 0) s_carry = 0u;
    __syncthreads();
    for (int base = 0; base < NNODES; base += 1024) {
        int i = base + t;
        uint32_t v = (i < NNODES) ? cnt[i] : 0u;
        lds[t] = v;
        __syncthreads();
        for (int off = 1; off < 1024; off <<= 1) {
            uint32_t add = (t >= off) ? lds[t - off] : 0u;
            __syncthreads();
            lds[t] += add;
            __syncthreads();
        }
        uint32_t incl  = lds[t];
        uint32_t total = lds[1023];
        uint32_t c     = s_carry;
        __syncthreads();
        if (i < NNODES) cnt[i] = incl - v + c;       // exclusive + carry
        if (t == 0) s_carry = c + total;
        __syncthreads();
    }
}

// Scatter edges into dst-sorted pair array; cnt[d] becomes end-offset of row d.
__global__ void fill_pairs(const int*   __restrict__ esrc,
                           const int*   __restrict__ edst,
                           const float* __restrict__ eval,
                           uint32_t*    __restrict__ cnt,
                           int2*        __restrict__ pairs) {
    int e = blockIdx.x * blockDim.x + threadIdx.x;   // NNZ threads
    if (e >= NNZ) return;
    int d = edst[e];
    uint32_t pos = atomicAdd(&cnt[d], 1u);
    pairs[pos] = make_int2(esrc[e], __float_as_int(eval[e]));
}

// One wave per dst row; lane = column. No atomics. 4-edge unroll for MLP.
__global__ __launch_bounds__(256) void spmm_gather(const uint32_t* __restrict__ rowend,
                                                   const int2*     __restrict__ pairs,
                                                   const float*    __restrict__ prev,
                                                   float*          __restrict__ cur) {
    int w    = (blockIdx.x * blockDim.x + threadIdx.x) >> 6;  // row id
    int lane = threadIdx.x & 63;
    if (w >= NNODES) return;
    uint32_t start = (w == 0) ? 0u : rowend[w - 1];
    uint32_t end   = rowend[w];
    float acc = 0.f;
    uint32_t i = start;
    for (; i + 4 <= end; i += 4) {
        int2 p0 = pairs[i + 0];
        int2 p1 = pairs[i + 1];
        int2 p2 = pairs[i + 2];
        int2 p3 = pairs[i + 3];
        float x0 = prev[(size_t)p0.x * OUTDIM + lane];
        float x1 = prev[(size_t)p1.x * OUTDIM + lane];
        float x2 = prev[(size_t)p2.x * OUTDIM + lane];
        float x3 = prev[(size_t)p3.x * OUTDIM + lane];
        acc = fmaf(x0, __int_as_float(p0.y), acc);
        acc = fmaf(x1, __int_as_float(p1.y), acc);
        acc = fmaf(x2, __int_as_float(p2.y), acc);
        acc = fmaf(x3, __int_as_float(p3.y), acc);
    }
    for (; i < end; ++i) {
        int2 p = pairs[i];
        acc = fmaf(prev[(size_t)p.x * OUTDIM + lane], __int_as_float(p.y), acc);
    }
    cur[(size_t)w * OUTDIM + lane] = acc;
}

// ---------- fallback (R1 proven path) if ws too small ----------
__global__ void init_out_full(const float* __restrict__ user_emb,
                              const float* __restrict__ item_emb,
                              float* __restrict__ out) {
    int t = blockIdx.x * blockDim.x + threadIdx.x;
    if (t >= NNODES * 64) return;
    int n = t >> 6;
    int c = (t & 63) << 2;
    float4 v = make_float4(0.f, 0.f, 0.f, 0.f);
    if (c < DIM) {
        const float* s = (n < U_NUM) ? (user_emb + (size_t)n * DIM + c)
                                     : (item_emb + (size_t)(n - U_NUM) * DIM + c);
        v = *(const float4*)s;
    }
    *(float4*)(out + (size_t)n * OUTDIM + c) = v;
}

__global__ void scatter_spmm(const int*   __restrict__ esrc,
                             const int*   __restrict__ edst,
                             const float* __restrict__ eval,
                             const float* __restrict__ prev,
                             float*       __restrict__ cur) {
    int t = blockIdx.x * blockDim.x + threadIdx.x;
    if (t >= NNZ * 16) return;
    int e = t >> 4;
    int j = (t & 15) << 2;
    int s = esrc[e];
    int d = edst[e];
    float v = eval[e];
    float4 x = *(const float4*)(prev + (size_t)s * OUTDIM + j);
    float* ap = cur + (size_t)d * OUTDIM + j;
    unsafeAtomicAdd(ap + 0, x.x * v);
    unsafeAtomicAdd(ap + 1, x.y * v);
    unsafeAtomicAdd(ap + 2, x.z * v);
    unsafeAtomicAdd(ap + 3, x.w * v);
}

extern "C" void kernel_launch(void* const* d_in, const int* in_sizes, int n_in,
                              void* d_out, int out_size, void* d_ws, size_t ws_size,
                              hipStream_t stream) {
    const float* user_emb = (const float*)d_in[0];
    const float* item_emb = (const float*)d_in[1];
    const float* eval     = (const float*)d_in[2];
    const int*   esrc     = (const int*)d_in[3];
    const int*   edst     = (const int*)d_in[4];
    float* out = (float*)d_out;                      // 200000 x 256 f32

    if (ws_size >= WS_NEEDED) {
        uint32_t* cnt   = (uint32_t*)d_ws;
        int2*     pairs = (int2*)((char*)d_ws + 800000);

        init_out<<<(NNODES * 16 + 255) / 256, 256, 0, stream>>>(user_emb, item_emb, out);
        zero_cnt<<<(NNODES + 255) / 256, 256, 0, stream>>>(cnt);
        hist<<<NNZ / 256, 256, 0, stream>>>(edst, cnt);
        scan_cnt<<<1, 1024, 0, stream>>>(cnt);
        fill_pairs<<<NNZ / 256, 256, 0, stream>>>(esrc, edst, eval, cnt, pairs);

        for (int l = 1; l <= 3; ++l) {
            spmm_gather<<<(NNODES * 64) / 256, 256, 0, stream>>>(
                cnt, pairs,
                out + (size_t)(l - 1) * DIM,
                out + (size_t)l * DIM);
        }
    } else {
        init_out_full<<<(NNODES * 64 + 255) / 256, 256, 0, stream>>>(user_emb, item_emb, out);
        for (int l = 1; l <= 3; ++l) {
            scatter_spmm<<<(NNZ * 16) / 256, 256, 0, stream>>>(
                esrc, edst, eval,
                out + (size_t)(l - 1) * DIM,
                out + (size_t)l * DIM);
        }
    }
}